// Round 16
// baseline (150.197 us; speedup 1.0000x reference)
//
#include <hip/hip_runtime.h>
#include <hip/hip_bf16.h>
#include <math.h>

typedef __bf16 bf16;
typedef __bf16 bf16x8 __attribute__((ext_vector_type(8)));
typedef float  f32x4  __attribute__((ext_vector_type(4)));

#define NB    2
#define NT    2048
#define NH    16
#define ND    64
#define NC    1024
#define NBT   4096   /* NB*NT */
#define NQT   32     /* NT/64 */

#define AS1C(p) ((const __attribute__((address_space(1))) void*)(p))
#define AS3(p)  ((__attribute__((address_space(3))) void*)(p))

#define MFMA(a,b,c) __builtin_amdgcn_mfma_f32_16x16x32_bf16(a, b, c, 0, 0, 0)

struct WPtrs { const float* p[6]; };

// ---------------- fused prep: X cast + 6 weight casts + rope table ----------------
__global__ void prep_kernel(const float* __restrict__ x, WPtrs w,
                            bf16* __restrict__ Xbf, bf16* __restrict__ Wcat,
                            float2* __restrict__ tbl)
{
    const int bid = blockIdx.x;
    if (bid < 4096) {
        const int i = (bid * 256 + threadIdx.x) * 4;
        float4 v = *reinterpret_cast<const float4*>(x + i);
        Xbf[i+0] = (bf16)v.x; Xbf[i+1] = (bf16)v.y;
        Xbf[i+2] = (bf16)v.z; Xbf[i+3] = (bf16)v.w;
    } else if (bid < 10240) {
        const int r   = bid - 4096;
        const int mat = r >> 10;                       // block-uniform
        const int off = ((r & 1023) * 256 + threadIdx.x) * 4;
        float4 v = *reinterpret_cast<const float4*>(w.p[mat] + off);
        bf16* d = Wcat + (size_t)mat * NC * NC + off;
        d[0] = (bf16)v.x; d[1] = (bf16)v.y; d[2] = (bf16)v.z; d[3] = (bf16)v.w;
    } else {
        const int i = (bid - 10240) * 256 + threadIdx.x;   // 0 .. NT*32-1
        const int t = i >> 5, j = i & 31;
        float invf = 1.0f / powf(10000.0f, (float)j * (1.0f/32.0f));
        float fr = (float)t * invf;
        float2 cs;
        cs.x = (float)(bf16)cosf(fr);
        cs.y = (float)(bf16)sinf(fr);
        tbl[i] = cs;
    }
}

// ---------------- projection GEMM: 128^2 tile, 3-slot half-K pipeline, 3 blk/CU ----
__global__ __launch_bounds__(256, 3)
void gemm_proj(const bf16* __restrict__ A, const bf16* __restrict__ Bw,
               bf16* __restrict__ qkv, const float2* __restrict__ tbl)
{
    __shared__ bf16 smem[3*8192];   // 48 KB: 3 slots x (A 8KB | B 8KB)

    const int tid  = threadIdx.x;
    const int lane = tid & 63;
    const int w    = tid >> 6;
    const int wr   = w >> 1;
    const int wc   = w & 1;

    const int id  = blockIdx.x;
    const int xcd = id & 7;
    const int r   = id >> 3;            // 0..159
    const int bx  = r >> 2;             // 0..39
    const int by  = xcd * 4 + (r & 3);  // 0..31
    const int row0 = by * 128, col0 = bx * 128;

    const int lo  = lane & 15;
    const int hi  = lane >> 4;

    const int hrow = w*16 + (lane >> 2);
    const int hcol = ((lane & 3) ^ ((lane >> 3) & 3)) * 8;

    f32x4 acc[4][4] = {};

    auto stageHalf = [&](int s, int slot) {
        char* base = (char*)smem + slot * 16384;
        const int k0 = s * 32;
        #pragma unroll
        for (int i = 0; i < 2; ++i) {
            __builtin_amdgcn_global_load_lds(
                AS1C(A + (size_t)(row0 + i*64 + hrow) * NC + k0 + hcol),
                AS3(base + i*4096 + w*1024), 16, 0, 0);
            __builtin_amdgcn_global_load_lds(
                AS1C(Bw + (size_t)(col0 + i*64 + hrow) * NC + k0 + hcol),
                AS3(base + 8192 + i*4096 + w*1024), 16, 0, 0);
        }
    };

    stageHalf(0, 0);
    stageHalf(1, 1);

    const int csw = (lo >> 1) & 3;
    int slot = 0;
    for (int s = 0; s < 32; ++s) {
        if (s < 31) asm volatile("s_waitcnt vmcnt(4)" ::: "memory");
        else        asm volatile("s_waitcnt vmcnt(0)" ::: "memory");
        __builtin_amdgcn_s_barrier();
        asm volatile("" ::: "memory");
        if (s + 2 < 32) {
            int nx = slot + 2; if (nx >= 3) nx -= 3;
            stageHalf(s + 2, nx);
        }

        const char* As = (const char*)smem + slot * 16384;
        const char* Bs = As + 8192;

        bf16x8 af[4], bfr[4];
        #pragma unroll
        for (int m = 0; m < 4; ++m) {
            const int ar = wr*64 + m*16 + lo;
            af[m] = *reinterpret_cast<const bf16x8*>(As + ar*64 + ((hi ^ csw) * 16));
        }
        #pragma unroll
        for (int n = 0; n < 4; ++n) {
            const int br = wc*64 + n*16 + lo;
            bfr[n] = *reinterpret_cast<const bf16x8*>(Bs + br*64 + ((hi ^ csw) * 16));
        }
        __builtin_amdgcn_s_setprio(1);
        #pragma unroll
        for (int m = 0; m < 4; ++m)
            #pragma unroll
            for (int n = 0; n < 4; ++n)
                acc[m][n] = MFMA(af[m], bfr[n], acc[m][n]);
        __builtin_amdgcn_s_setprio(0);

        slot += 1; if (slot >= 3) slot -= 3;
    }
    __syncthreads();   // full drain before epilogue reuses smem

    bf16* Ct = smem;
    const int p  = col0 >> 10;
    const int h0 = (col0 >> 6) & (NH-1);
    const int rb = hi * 4;

    if (p < 4) {
        const float qsc = (p == 0 || p == 2) ? 0.015625f : 1.0f;
        #pragma unroll
        for (int m = 0; m < 4; ++m)
            #pragma unroll
            for (int r2 = 0; r2 < 4; ++r2) {
                const int rl = wr*64 + m*16 + rb + r2;
                const int t  = (row0 + rl) & (NT-1);
                const unsigned key = ((unsigned)(rl >> 2) & 3) << 5;
                #pragma unroll
                for (int n = 0; n < 2; ++n) {
                    const int j = n*16 + lo;
                    float2 cs = tbl[t*32 + j];
                    float a1 = acc[m][n][r2];
                    float a2 = acc[m][n+2][r2];
                    const int c1 = wc*64 + j;
                    const int c2 = c1 + 32;
                    *(bf16*)((char*)Ct + (unsigned)(rl*256 + (((unsigned)c1*2) ^ key)))
                        = (bf16)((a1*cs.x + a2*cs.y) * qsc);
                    *(bf16*)((char*)Ct + (unsigned)(rl*256 + (((unsigned)c2*2) ^ key)))
                        = (bf16)((a2*cs.x - a1*cs.y) * qsc);
                }
            }
        __syncthreads();
        #pragma unroll
        for (int it = 0; it < 8; ++it) {
            const int chunk = it*256 + tid;
            const int rl = chunk >> 4;
            const int cc = chunk & 15;
            const unsigned key = ((unsigned)(rl >> 2) & 3) << 5;
            bf16x8 val = *reinterpret_cast<const bf16x8*>(
                (const char*)Ct + ((unsigned)rl*256 + (((unsigned)cc*16) ^ key)));
            const int rowg = row0 + rl;
            const int b = rowg >> 11;
            const int t = rowg & (NT-1);
            const int hh = h0 + (cc >> 3);
            const int d  = (cc & 7) * 8;
            *reinterpret_cast<bf16x8*>(
                qkv + ((((size_t)p*NB + b)*NH + hh)*NT + t)*ND + d) = val;
        }
    } else {
        #pragma unroll
        for (int m = 0; m < 4; ++m)
            #pragma unroll
            for (int r2 = 0; r2 < 4; ++r2) {
                const int rl = wr*64 + m*16 + rb + r2;
                #pragma unroll
                for (int n = 0; n < 4; ++n) {
                    const int c = wc*64 + n*16 + lo;
                    *(bf16*)((char*)Ct + (unsigned)(c*256 + (((unsigned)rl*2) ^ ((c&7)<<4))))
                        = (bf16)acc[m][n][r2];
                }
            }
        __syncthreads();
        const int b  = row0 >> 11;
        const int t0 = row0 & (NT-1);
        #pragma unroll
        for (int it = 0; it < 8; ++it) {
            const int chunk = it*256 + tid;
            const int c   = chunk >> 4;
            const int tcc = chunk & 15;
            bf16x8 val = *reinterpret_cast<const bf16x8*>(
                (const char*)Ct + (unsigned)(c*256 + (((unsigned)tcc*16) ^ ((c&7)<<4))));
            const int hh = h0 + (c >> 6);
            const int d  = c & 63;
            *reinterpret_cast<bf16x8*>(
                qkv + (((size_t)4*NB + b)*NH + hh)*(size_t)NT*ND
                    + (size_t)d*NT + t0 + tcc*8) = val;
        }
    }
}

// ---------------- output GEMM: 128x64 tile, 4-slot half-K pipeline, 512 blocks ----
__global__ __launch_bounds__(256)
void gemm_out(const bf16* __restrict__ A, const bf16* __restrict__ Bw,
              float* __restrict__ Cp)
{
    __shared__ bf16 smem[4*6144];   // 48 KB

    const int tid  = threadIdx.x;
    const int lane = tid & 63;
    const int w    = tid >> 6;
    const int wr   = w >> 1;
    const int wc   = w & 1;
    const int row0 = blockIdx.y * 128;
    const int col0 = blockIdx.x * 64;

    const int lo  = lane & 15;
    const int hi  = lane >> 4;

    const int hrow = w*16 + (lane >> 2);
    const int hcol = ((lane & 3) ^ ((lane >> 3) & 3)) * 8;

    f32x4 acc[4][2] = {};

    auto stageHalf = [&](int s) {
        char* base = (char*)smem + (s & 3) * 12288;
        const int k0 = s * 32;
        #pragma unroll
        for (int i = 0; i < 2; ++i)
            __builtin_amdgcn_global_load_lds(
                AS1C(A + (size_t)(row0 + i*64 + hrow) * NC + k0 + hcol),
                AS3(base + i*4096 + w*1024), 16, 0, 0);
        __builtin_amdgcn_global_load_lds(
            AS1C(Bw + (size_t)(col0 + hrow) * NC + k0 + hcol),
            AS3(base + 8192 + w*1024), 16, 0, 0);
    };

    stageHalf(0);
    stageHalf(1);

    const int csw = (lo >> 1) & 3;
    for (int s = 0; s < 32; ++s) {
        if (s < 31) asm volatile("s_waitcnt vmcnt(3)" ::: "memory");
        else        asm volatile("s_waitcnt vmcnt(0)" ::: "memory");
        __builtin_amdgcn_s_barrier();
        asm volatile("" ::: "memory");
        if (s + 2 < 32) stageHalf(s + 2);

        const char* As = (const char*)smem + (s & 3) * 12288;
        const char* Bs = As + 8192;

        bf16x8 af[4], bfr[2];
        #pragma unroll
        for (int m = 0; m < 4; ++m) {
            const int ar = wr*64 + m*16 + lo;
            af[m] = *reinterpret_cast<const bf16x8*>(As + ar*64 + ((hi ^ csw) * 16));
        }
        #pragma unroll
        for (int n = 0; n < 2; ++n) {
            const int br = wc*32 + n*16 + lo;
            bfr[n] = *reinterpret_cast<const bf16x8*>(Bs + br*64 + ((hi ^ csw) * 16));
        }
        __builtin_amdgcn_s_setprio(1);
        #pragma unroll
        for (int m = 0; m < 4; ++m)
            #pragma unroll
            for (int n = 0; n < 2; ++n)
                acc[m][n] = MFMA(af[m], bfr[n], acc[m][n]);
        __builtin_amdgcn_s_setprio(0);
    }

    const int rb = hi * 4;
    #pragma unroll
    for (int m = 0; m < 4; ++m)
        #pragma unroll
        for (int n = 0; n < 2; ++n)
            #pragma unroll
            for (int r = 0; r < 4; ++r) {
                int row = row0 + wr*64 + m*16 + rb + r;
                int col = col0 + wc*32 + n*16 + lo;
                Cp[(size_t)row * NC + col] = acc[m][n][r];
            }
}

// ---------------- fused bilinear attention: 8 waves, KVBLK=128 ----------------
// 512 threads. Waves 0-3 own tile qb (rows (w&3)*16), waves 4-7 own tile qa:
// the two tiles process CONCURRENTLY each pass. K-chunk per pass = 128 ->
// pass counts 9..16 (straggler halved from 32). 2 DMA slots (K1/K2/V^T 16KB
// each), counted schedule: vmcnt(0) -> s_barrier -> stage(ckt+1) -> compute.
__global__ __launch_bounds__(512, 2)
void attn_kernel(const bf16* __restrict__ qkv, bf16* __restrict__ Y)
{
    __shared__ bf16 K1s[2][128*64];   // [t][d], 16 KB/slot
    __shared__ bf16 K2s[2][128*64];
    __shared__ bf16 Vts[2][64*128];   // [d][t] (from V^T), 16 KB/slot
    __shared__ bf16 Pl [8][16*128];   // per-wave P, 4 KB

    const int tid  = threadIdx.x;     // 0..511
    const int lane = tid & 63;
    const int w    = tid >> 6;        // 0..7
    const int ta   = w >> 2;          // 0: tile qb, 1: tile qa
    const int w4   = w & 3;

    // XCD-locality decode: 4 (b,h) pairs per XCD, 16 blocks each
    const int lin  = blockIdx.x;           // 0..511
    const int xcd  = lin & 7;
    const int slot = lin >> 3;             // 0..63
    const int pair = xcd * 4 + (slot >> 4);   // 0..31
    const int qa   = slot & 15;
    const int h    = pair >> 1;
    const int b    = pair & 1;
    const int qb   = NQT - 1 - qa;
    const int qw   = ta ? qa : qb;         // this wave's q-tile

    const size_t plane = (size_t)NB * NH * NT * ND;
    const size_t bh    = ((size_t)b * NH + h) * (size_t)NT * ND;
    const bf16* Q1 = qkv + 0*plane + bh;
    const bf16* K1 = qkv + 1*plane + bh;
    const bf16* Q2 = qkv + 2*plane + bh;
    const bf16* K2 = qkv + 3*plane + bh;
    const bf16* V  = qkv + 4*plane + bh;   // V^T slab: [d][t]

    const int lo  = lane & 15;
    const int hi  = lane >> 4;
    const int hi8 = hi * 8;
    const int qg0 = qw*64 + w4*16;         // wave's first q-row

    // Q fragments for this wave's tile (pre-scaled by 1/64 at projection)
    bf16x8 q1f[2], q2f[2];
    #pragma unroll
    for (int dd = 0; dd < 2; ++dd) {
        const size_t ra = (size_t)(qg0 + lo) * ND + dd*32 + hi8;
        q1f[dd] = *reinterpret_cast<const bf16x8*>(Q1 + ra);
        q2f[dd] = *reinterpret_cast<const bf16x8*>(Q2 + ra);
    }

    f32x4 yacc[4] = {};

    // K staging: 512 threads cover 64 t-rows per issue; 2 issues = 128 rows.
    const int srow = tid >> 3;                       // 0..63
    const int ssw  = ((tid & 7) ^ (srow & 7)) * 8;   // pre-swizzled d-col
    // V^T staging: d = j*32 + tid>>4, chunk = tid&15 pre-swizzled by d&15
    const int vdl = tid >> 4;                        // 0..31
    const int vsc = ((tid & 15) ^ (vdl & 15)) * 8;   // (d&15) == (vdl&15) since j*32 keeps low 4 bits

    auto stage = [&](int buf, int k0) {
        #pragma unroll
        for (int j = 0; j < 2; ++j) {
            const unsigned loff = (unsigned)(j*8192 + w*1024);
            __builtin_amdgcn_global_load_lds(
                AS1C(K1 + (size_t)(k0 + j*64 + srow) * ND + ssw),
                AS3((char*)K1s[buf] + loff), 16, 0, 0);
            __builtin_amdgcn_global_load_lds(
                AS1C(K2 + (size_t)(k0 + j*64 + srow) * ND + ssw),
                AS3((char*)K2s[buf] + loff), 16, 0, 0);
            __builtin_amdgcn_global_load_lds(
                AS1C(V + (size_t)(j*32 + vdl) * NT + k0 + vsc),
                AS3((char*)Vts[buf] + loff), 16, 0, 0);
        }
    };

    const int nck = (qb >> 1) + 1;   // passes: 9..16
    const int mya = qw >> 1;         // last active chunk for this wave

    stage(0, 0);

    int cur = 0;
    for (int ckt = 0; ckt < nck; ++ckt) {
        asm volatile("s_waitcnt vmcnt(0)" ::: "memory");
        __builtin_amdgcn_s_barrier();
        asm volatile("" ::: "memory");
        if (ckt + 1 < nck) stage(cur ^ 1, (ckt + 1) * 128);

        if (ckt <= mya) {
            const char* K1b = (const char*)K1s[cur];
            const char* K2b = (const char*)K2s[cur];

            // --- S1/S2: 16 q-rows x 128 k-cols ---
            f32x4 s1[8] = {}, s2[8] = {};
            __builtin_amdgcn_s_setprio(1);
            #pragma unroll
            for (int dd = 0; dd < 2; ++dd)
                #pragma unroll
                for (int sub = 0; sub < 8; ++sub) {
                    const unsigned kb = (unsigned)((sub*16 + lo)*128 + (((dd*4 + hi) ^ (lo & 7)) * 16));
                    bf16x8 k1f = *reinterpret_cast<const bf16x8*>(K1b + kb);
                    bf16x8 k2f = *reinterpret_cast<const bf16x8*>(K2b + kb);
                    s1[sub] = MFMA(q1f[dd], k1f, s1[sub]);
                    s2[sub] = MFMA(q2f[dd], k2f, s2[sub]);
                }
            __builtin_amdgcn_s_setprio(0);

            // --- combine -> P (bf16), element mask only on diagonal chunk ---
            const bool diag = (ckt == mya);
            #pragma unroll
            for (int sub = 0; sub < 8; ++sub)
                #pragma unroll
                for (int r = 0; r < 4; ++r) {
                    const int row = hi*4 + r;
                    const int col = sub*16 + lo;
                    const unsigned byte = (unsigned)(row*256 + (((col>>3) ^ (row&15))*16) + (col&7)*2);
                    float pv = s1[sub][r] * s2[sub][r];
                    if (diag && (ckt*128 + col > qg0 + row)) pv = 0.0f;
                    *(bf16*)((char*)Pl[w] + byte) = (bf16)pv;
                }
            asm volatile("s_waitcnt lgkmcnt(0)" ::: "memory");
            __builtin_amdgcn_sched_barrier(0);

            // --- Y += P * V ---
            const char* Vb = (const char*)Vts[cur];
            __builtin_amdgcn_s_setprio(1);
            #pragma unroll
            for (int ks = 0; ks < 4; ++ks) {
                const unsigned pby = (unsigned)(lo*256 + (((ks*4 + hi) ^ lo) * 16));
                bf16x8 pf = *reinterpret_cast<const bf16x8*>((const char*)Pl[w] + pby);
                #pragma unroll
                for (int n = 0; n < 4; ++n) {
                    const unsigned vby = (unsigned)((n*16 + lo)*256 + (((ks*4 + hi) ^ lo) * 16));
                    bf16x8 vf = *reinterpret_cast<const bf16x8*>(Vb + vby);
                    yacc[n] = MFMA(pf, vf, yacc[n]);
                }
            }
            __builtin_amdgcn_s_setprio(0);
        }
        cur ^= 1;
    }

    // --- writeout via swizzled per-wave staging, 16B coalesced stores ---
    #pragma unroll
    for (int n = 0; n < 4; ++n)
        #pragma unroll
        for (int r = 0; r < 4; ++r) {
            const int row = hi*4 + r;
            const int col = n*16 + lo;
            const unsigned byte = (unsigned)(row*256 + (((col>>3) ^ (row&7))*16) + (col&7)*2);
            *(bf16*)((char*)Pl[w] + byte) = (bf16)yacc[n][r];
        }
    asm volatile("s_waitcnt lgkmcnt(0)" ::: "memory");
    __builtin_amdgcn_sched_barrier(0);
    #pragma unroll
    for (int pass = 0; pass < 2; ++pass) {
        const int idx = pass*64 + lane;
        const int row = idx >> 3;
        const int cc  = idx & 7;
        bf16x8 val = *reinterpret_cast<const bf16x8*>(
            (const char*)Pl[w] + row*256 + ((cc ^ (row&7))*16));
        const int t = qg0 + row;
        const int c = h*ND + cc*8;
        *reinterpret_cast<bf16x8*>(Y + ((size_t)b*NT + t)*NC + c) = val;
    }
}

// ---------------- launch ----------------
extern "C" void kernel_launch(void* const* d_in, const int* in_sizes, int n_in,
                              void* d_out, int out_size, void* d_ws, size_t ws_size,
                              hipStream_t stream)
{
    const float* x = (const float*)d_in[0];

    char* ws = (char*)d_ws;
    bf16*   Xbf   = (bf16*)ws;                                            // 8 MB
    bf16*   Wcat  = (bf16*)(ws + (size_t)NBT*NC*2);                       // 12 MB (6 mats)
    bf16*   QKV   = (bf16*)(ws + (size_t)NBT*NC*2 + (size_t)6*NC*NC*2);   // 40 MB
    bf16*   Ybf   = (bf16*)((char*)QKV + (size_t)5*NBT*NC*2);             // 8 MB
    float2* tbl   = (float2*)((char*)Ybf + (size_t)NBT*NC*2);             // 512 KB
    bf16*   Woutb = Wcat + (size_t)5*NC*NC;

    WPtrs wp;
    wp.p[0] = (const float*)d_in[1]; wp.p[1] = (const float*)d_in[2];
    wp.p[2] = (const float*)d_in[3]; wp.p[3] = (const float*)d_in[4];
    wp.p[4] = (const float*)d_in[5]; wp.p[5] = (const float*)d_in[6];

    // fused prep: X cast + weight casts + rope table
    prep_kernel<<<dim3(10496), 256, 0, stream>>>(x, wp, Xbf, Wcat, tbl);

    // fused 5-projection GEMM (128^2 tile, 3-slot pipeline, 3 blk/CU)
    gemm_proj<<<dim3(1280), 256, 0, stream>>>(Xbf, Wcat, QKV, tbl);
    // fused bilinear attention -> Ybf [b][t][c]  (8 waves, KVBLK=128)
    attn_kernel<<<dim3(512), 512, 0, stream>>>(QKV, Ybf);
    // output projection -> fp32 d_out (128x64 tiles, 4-slot pipeline, 2 blk/CU)
    gemm_out<<<dim3(NC/64, NBT/128), 256, 0, stream>>>(Ybf, Woutb, (float*)d_out);
}

// Round 17
// 137.552 us; speedup vs baseline: 1.0919x; 1.0919x over previous
//
#include <hip/hip_runtime.h>
#include <hip/hip_bf16.h>
#include <math.h>

typedef __bf16 bf16;
typedef __bf16 bf16x8 __attribute__((ext_vector_type(8)));
typedef float  f32x4  __attribute__((ext_vector_type(4)));

#define NB    2
#define NT    2048
#define NH    16
#define ND    64
#define NC    1024
#define NBT   4096   /* NB*NT */
#define NQT   32     /* NT/64 */

#define AS1C(p) ((const __attribute__((address_space(1))) void*)(p))
#define AS3(p)  ((__attribute__((address_space(3))) void*)(p))

#define MFMA(a,b,c) __builtin_amdgcn_mfma_f32_16x16x32_bf16(a, b, c, 0, 0, 0)

struct WPtrs { const float* p[6]; };

// ---------------- fused prep: X cast + 6 weight casts + rope table ----------------
__global__ void prep_kernel(const float* __restrict__ x, WPtrs w,
                            bf16* __restrict__ Xbf, bf16* __restrict__ Wcat,
                            float2* __restrict__ tbl)
{
    const int bid = blockIdx.x;
    if (bid < 4096) {
        const int i = (bid * 256 + threadIdx.x) * 4;
        float4 v = *reinterpret_cast<const float4*>(x + i);
        Xbf[i+0] = (bf16)v.x; Xbf[i+1] = (bf16)v.y;
        Xbf[i+2] = (bf16)v.z; Xbf[i+3] = (bf16)v.w;
    } else if (bid < 10240) {
        const int r   = bid - 4096;
        const int mat = r >> 10;                       // block-uniform
        const int off = ((r & 1023) * 256 + threadIdx.x) * 4;
        float4 v = *reinterpret_cast<const float4*>(w.p[mat] + off);
        bf16* d = Wcat + (size_t)mat * NC * NC + off;
        d[0] = (bf16)v.x; d[1] = (bf16)v.y; d[2] = (bf16)v.z; d[3] = (bf16)v.w;
    } else {
        const int i = (bid - 10240) * 256 + threadIdx.x;   // 0 .. NT*32-1
        const int t = i >> 5, j = i & 31;
        float invf = 1.0f / powf(10000.0f, (float)j * (1.0f/32.0f));
        float fr = (float)t * invf;
        float2 cs;
        cs.x = (float)(bf16)cosf(fr);
        cs.y = (float)(bf16)sinf(fr);
        tbl[i] = cs;
    }
}

// ---------------- projection GEMM: 128^2 tile, 3-slot half-K pipeline, 3 blk/CU ----
__global__ __launch_bounds__(256, 3)
void gemm_proj(const bf16* __restrict__ A, const bf16* __restrict__ Bw,
               bf16* __restrict__ qkv, const float2* __restrict__ tbl)
{
    __shared__ bf16 smem[3*8192];   // 48 KB: 3 slots x (A 8KB | B 8KB)

    const int tid  = threadIdx.x;
    const int lane = tid & 63;
    const int w    = tid >> 6;
    const int wr   = w >> 1;
    const int wc   = w & 1;

    const int id  = blockIdx.x;
    const int xcd = id & 7;
    const int r   = id >> 3;            // 0..159
    const int bx  = r >> 2;             // 0..39
    const int by  = xcd * 4 + (r & 3);  // 0..31
    const int row0 = by * 128, col0 = bx * 128;

    const int lo  = lane & 15;
    const int hi  = lane >> 4;

    const int hrow = w*16 + (lane >> 2);
    const int hcol = ((lane & 3) ^ ((lane >> 3) & 3)) * 8;

    f32x4 acc[4][4] = {};

    auto stageHalf = [&](int s, int slot) {
        char* base = (char*)smem + slot * 16384;
        const int k0 = s * 32;
        #pragma unroll
        for (int i = 0; i < 2; ++i) {
            __builtin_amdgcn_global_load_lds(
                AS1C(A + (size_t)(row0 + i*64 + hrow) * NC + k0 + hcol),
                AS3(base + i*4096 + w*1024), 16, 0, 0);
            __builtin_amdgcn_global_load_lds(
                AS1C(Bw + (size_t)(col0 + i*64 + hrow) * NC + k0 + hcol),
                AS3(base + 8192 + i*4096 + w*1024), 16, 0, 0);
        }
    };

    stageHalf(0, 0);
    stageHalf(1, 1);

    const int csw = (lo >> 1) & 3;
    int slot = 0;
    for (int s = 0; s < 32; ++s) {
        if (s < 31) asm volatile("s_waitcnt vmcnt(4)" ::: "memory");
        else        asm volatile("s_waitcnt vmcnt(0)" ::: "memory");
        __builtin_amdgcn_s_barrier();
        asm volatile("" ::: "memory");
        if (s + 2 < 32) {
            int nx = slot + 2; if (nx >= 3) nx -= 3;
            stageHalf(s + 2, nx);
        }

        const char* As = (const char*)smem + slot * 16384;
        const char* Bs = As + 8192;

        bf16x8 af[4], bfr[4];
        #pragma unroll
        for (int m = 0; m < 4; ++m) {
            const int ar = wr*64 + m*16 + lo;
            af[m] = *reinterpret_cast<const bf16x8*>(As + ar*64 + ((hi ^ csw) * 16));
        }
        #pragma unroll
        for (int n = 0; n < 4; ++n) {
            const int br = wc*64 + n*16 + lo;
            bfr[n] = *reinterpret_cast<const bf16x8*>(Bs + br*64 + ((hi ^ csw) * 16));
        }
        __builtin_amdgcn_s_setprio(1);
        #pragma unroll
        for (int m = 0; m < 4; ++m)
            #pragma unroll
            for (int n = 0; n < 4; ++n)
                acc[m][n] = MFMA(af[m], bfr[n], acc[m][n]);
        __builtin_amdgcn_s_setprio(0);

        slot += 1; if (slot >= 3) slot -= 3;
    }
    __syncthreads();   // full drain before epilogue reuses smem

    bf16* Ct = smem;
    const int p  = col0 >> 10;
    const int h0 = (col0 >> 6) & (NH-1);
    const int rb = hi * 4;

    if (p < 4) {
        const float qsc = (p == 0 || p == 2) ? 0.015625f : 1.0f;
        #pragma unroll
        for (int m = 0; m < 4; ++m)
            #pragma unroll
            for (int r2 = 0; r2 < 4; ++r2) {
                const int rl = wr*64 + m*16 + rb + r2;
                const int t  = (row0 + rl) & (NT-1);
                const unsigned key = ((unsigned)(rl >> 2) & 3) << 5;
                #pragma unroll
                for (int n = 0; n < 2; ++n) {
                    const int j = n*16 + lo;
                    float2 cs = tbl[t*32 + j];
                    float a1 = acc[m][n][r2];
                    float a2 = acc[m][n+2][r2];
                    const int c1 = wc*64 + j;
                    const int c2 = c1 + 32;
                    *(bf16*)((char*)Ct + (unsigned)(rl*256 + (((unsigned)c1*2) ^ key)))
                        = (bf16)((a1*cs.x + a2*cs.y) * qsc);
                    *(bf16*)((char*)Ct + (unsigned)(rl*256 + (((unsigned)c2*2) ^ key)))
                        = (bf16)((a2*cs.x - a1*cs.y) * qsc);
                }
            }
        __syncthreads();
        #pragma unroll
        for (int it = 0; it < 8; ++it) {
            const int chunk = it*256 + tid;
            const int rl = chunk >> 4;
            const int cc = chunk & 15;
            const unsigned key = ((unsigned)(rl >> 2) & 3) << 5;
            bf16x8 val = *reinterpret_cast<const bf16x8*>(
                (const char*)Ct + ((unsigned)rl*256 + (((unsigned)cc*16) ^ key)));
            const int rowg = row0 + rl;
            const int b = rowg >> 11;
            const int t = rowg & (NT-1);
            const int hh = h0 + (cc >> 3);
            const int d  = (cc & 7) * 8;
            *reinterpret_cast<bf16x8*>(
                qkv + ((((size_t)p*NB + b)*NH + hh)*NT + t)*ND + d) = val;
        }
    } else {
        #pragma unroll
        for (int m = 0; m < 4; ++m)
            #pragma unroll
            for (int r2 = 0; r2 < 4; ++r2) {
                const int rl = wr*64 + m*16 + rb + r2;
                #pragma unroll
                for (int n = 0; n < 4; ++n) {
                    const int c = wc*64 + n*16 + lo;
                    *(bf16*)((char*)Ct + (unsigned)(c*256 + (((unsigned)rl*2) ^ ((c&7)<<4))))
                        = (bf16)acc[m][n][r2];
                }
            }
        __syncthreads();
        const int b  = row0 >> 11;
        const int t0 = row0 & (NT-1);
        #pragma unroll
        for (int it = 0; it < 8; ++it) {
            const int chunk = it*256 + tid;
            const int c   = chunk >> 4;
            const int tcc = chunk & 15;
            bf16x8 val = *reinterpret_cast<const bf16x8*>(
                (const char*)Ct + (unsigned)(c*256 + (((unsigned)tcc*16) ^ ((c&7)<<4))));
            const int hh = h0 + (c >> 6);
            const int d  = c & 63;
            *reinterpret_cast<bf16x8*>(
                qkv + (((size_t)4*NB + b)*NH + hh)*(size_t)NT*ND
                    + (size_t)d*NT + t0 + tcc*8) = val;
        }
    }
}

// ---------------- output GEMM: 128x64 tile, 4-slot, 3-deep prefetch ----------------
__global__ __launch_bounds__(256)
void gemm_out(const bf16* __restrict__ A, const bf16* __restrict__ Bw,
              float* __restrict__ Cp)
{
    __shared__ bf16 smem[4*6144];   // 48 KB

    const int tid  = threadIdx.x;
    const int lane = tid & 63;
    const int w    = tid >> 6;
    const int wr   = w >> 1;
    const int wc   = w & 1;
    const int row0 = blockIdx.y * 128;
    const int col0 = blockIdx.x * 64;

    const int lo  = lane & 15;
    const int hi  = lane >> 4;

    const int hrow = w*16 + (lane >> 2);
    const int hcol = ((lane & 3) ^ ((lane >> 3) & 3)) * 8;

    f32x4 acc[4][2] = {};

    auto stageHalf = [&](int s) {
        char* base = (char*)smem + (s & 3) * 12288;
        const int k0 = s * 32;
        #pragma unroll
        for (int i = 0; i < 2; ++i)
            __builtin_amdgcn_global_load_lds(
                AS1C(A + (size_t)(row0 + i*64 + hrow) * NC + k0 + hcol),
                AS3(base + i*4096 + w*1024), 16, 0, 0);
        __builtin_amdgcn_global_load_lds(
            AS1C(Bw + (size_t)(col0 + hrow) * NC + k0 + hcol),
            AS3(base + 8192 + w*1024), 16, 0, 0);
    };

    // 3-deep prefetch: stages 0,1,2 in flight; stage(s+3) issued at step s
    stageHalf(0);
    stageHalf(1);
    stageHalf(2);

    const int csw = (lo >> 1) & 3;
    for (int s = 0; s < 32; ++s) {
        if (s < 30)      asm volatile("s_waitcnt vmcnt(6)" ::: "memory");
        else if (s == 30) asm volatile("s_waitcnt vmcnt(3)" ::: "memory");
        else             asm volatile("s_waitcnt vmcnt(0)" ::: "memory");
        __builtin_amdgcn_s_barrier();
        asm volatile("" ::: "memory");
        if (s + 3 < 32) stageHalf(s + 3);

        const char* As = (const char*)smem + (s & 3) * 12288;
        const char* Bs = As + 8192;

        bf16x8 af[4], bfr[2];
        #pragma unroll
        for (int m = 0; m < 4; ++m) {
            const int ar = wr*64 + m*16 + lo;
            af[m] = *reinterpret_cast<const bf16x8*>(As + ar*64 + ((hi ^ csw) * 16));
        }
        #pragma unroll
        for (int n = 0; n < 2; ++n) {
            const int br = wc*32 + n*16 + lo;
            bfr[n] = *reinterpret_cast<const bf16x8*>(Bs + br*64 + ((hi ^ csw) * 16));
        }
        __builtin_amdgcn_s_setprio(1);
        #pragma unroll
        for (int m = 0; m < 4; ++m)
            #pragma unroll
            for (int n = 0; n < 2; ++n)
                acc[m][n] = MFMA(af[m], bfr[n], acc[m][n]);
        __builtin_amdgcn_s_setprio(0);
    }

    const int rb = hi * 4;
    #pragma unroll
    for (int m = 0; m < 4; ++m)
        #pragma unroll
        for (int n = 0; n < 2; ++n)
            #pragma unroll
            for (int r = 0; r < 4; ++r) {
                int row = row0 + wr*64 + m*16 + rb + r;
                int col = col0 + wc*32 + n*16 + lo;
                Cp[(size_t)row * NC + col] = acc[m][n][r];
            }
}

// ---------------- fused bilinear attention (R15 version, verified 59.7 us) ----------
// Triple-buffered K/V staging, counted vmcnt(6) at pass top, raw s_barrier.
__global__ __launch_bounds__(256, 2)
void attn_kernel(const bf16* __restrict__ qkv, bf16* __restrict__ Y)
{
    __shared__ bf16 K1s[3*4096];
    __shared__ bf16 K2s[3*4096];
    __shared__ bf16 Vts[3*4096];
    __shared__ bf16 Pl [4][1024];

    const int tid  = threadIdx.x;
    const int lane = tid & 63;
    const int w    = tid >> 6;

    // XCD-locality decode: 4 (b,h) pairs per XCD, 16 blocks each
    const int lin  = blockIdx.x;           // 0..511
    const int xcd  = lin & 7;
    const int slot = lin >> 3;             // 0..63
    const int pair = xcd * 4 + (slot >> 4);   // 0..31
    const int qa   = slot & 15;
    const int h    = pair >> 1;
    const int b    = pair & 1;
    const int qb   = NQT - 1 - qa;

    const size_t plane = (size_t)NB * NH * NT * ND;
    const size_t bh    = ((size_t)b * NH + h) * (size_t)NT * ND;
    const bf16* Q1 = qkv + 0*plane + bh;
    const bf16* K1 = qkv + 1*plane + bh;
    const bf16* Q2 = qkv + 2*plane + bh;
    const bf16* K2 = qkv + 3*plane + bh;
    const bf16* V  = qkv + 4*plane + bh;   // V^T slab: [d][t]

    const int lo  = lane & 15;
    const int hi  = lane >> 4;
    const int hi8 = hi * 8;

    bf16x8 q1fa[2], q2fa[2], q1fb[2], q2fb[2];
    #pragma unroll
    for (int dd = 0; dd < 2; ++dd) {
        const size_t ra  = (size_t)(qa*64 + w*16 + lo) * ND + dd*32 + hi8;
        const size_t rbq = (size_t)(qb*64 + w*16 + lo) * ND + dd*32 + hi8;
        q1fa[dd] = *reinterpret_cast<const bf16x8*>(Q1 + ra);
        q2fa[dd] = *reinterpret_cast<const bf16x8*>(Q2 + ra);
        q1fb[dd] = *reinterpret_cast<const bf16x8*>(Q1 + rbq);
        q2fb[dd] = *reinterpret_cast<const bf16x8*>(Q2 + rbq);
    }

    f32x4 yacca[4] = {}, yaccb[4] = {};

    const int srow = tid >> 3;
    const int ssw  = ((tid & 7) ^ (srow & 7)) * 8;

    auto stageK = [&](int buf, int k0) {
        #pragma unroll
        for (int i = 0; i < 2; ++i) {
            const unsigned loff = (unsigned)(buf*8192 + i*4096 + w*1024);
            __builtin_amdgcn_global_load_lds(
                AS1C(K1 + (size_t)(k0 + i*32 + srow) * ND + ssw),
                AS3((char*)K1s + loff), 16, 0, 0);
            __builtin_amdgcn_global_load_lds(
                AS1C(K2 + (size_t)(k0 + i*32 + srow) * ND + ssw),
                AS3((char*)K2s + loff), 16, 0, 0);
        }
    };
    auto stageVT = [&](int buf, int k0) {
        #pragma unroll
        for (int i = 0; i < 2; ++i) {
            const int inst = w*2 + i;
            const int d    = inst*8 + (lane >> 3);
            const int sc   = ((lane & 7) ^ ((lane >> 3) & 7)) * 8;
            __builtin_amdgcn_global_load_lds(
                AS1C(V + (size_t)d * NT + k0 + sc),
                AS3((char*)Vts + (unsigned)(buf*8192 + inst*1024)), 16, 0, 0);
        }
    };

    // prologue: slots 0 and 1 in flight (qb >= 16 always)
    stageK(0, 0);  stageVT(0, 0);
    stageK(1, 64); stageVT(1, 64);

    int cur = 0;
    for (int kt = 0; kt <= qb; ++kt) {
        // stage(kt) must be landed; stage(kt+1) (6 loads) may stay in flight
        if (kt < qb) asm volatile("s_waitcnt vmcnt(6)" ::: "memory");
        else         asm volatile("s_waitcnt vmcnt(0)" ::: "memory");
        __builtin_amdgcn_s_barrier();
        asm volatile("" ::: "memory");
        if (kt + 2 <= qb) {
            int nx = cur + 2; if (nx >= 3) nx -= 3;
            stageK(nx, (kt + 2) * 64);
            stageVT(nx, (kt + 2) * 64);
        }

        const bool doA = (kt <= qa);
        const bf16* K1b = K1s + cur*4096;
        const bf16* K2b = K2s + cur*4096;
        const char* Vb  = (const char*)Vts + cur*8192;

        // --- S1/S2 for both q-tiles (K fragments shared) ---
        f32x4 s1a[4] = {}, s2a[4] = {}, s1b[4] = {}, s2b[4] = {};
        __builtin_amdgcn_s_setprio(1);
        #pragma unroll
        for (int dd = 0; dd < 2; ++dd)
            #pragma unroll
            for (int sub = 0; sub < 4; ++sub) {
                const unsigned kb = (unsigned)((sub*16 + lo)*128 + (((dd*4 + hi) ^ (lo & 7)) * 16));
                bf16x8 k1f = *reinterpret_cast<const bf16x8*>((const char*)K1b + kb);
                bf16x8 k2f = *reinterpret_cast<const bf16x8*>((const char*)K2b + kb);
                s1b[sub] = MFMA(q1fb[dd], k1f, s1b[sub]);
                s2b[sub] = MFMA(q2fb[dd], k2f, s2b[sub]);
                if (doA) {
                    s1a[sub] = MFMA(q1fa[dd], k1f, s1a[sub]);
                    s2a[sub] = MFMA(q2fa[dd], k2f, s2a[sub]);
                }
            }
        __builtin_amdgcn_s_setprio(0);

        #define COMBINE(S1, S2, DIAG)                                                  \
            _Pragma("unroll")                                                          \
            for (int sub = 0; sub < 4; ++sub)                                          \
                _Pragma("unroll")                                                      \
                for (int r = 0; r < 4; ++r) {                                          \
                    const int row = hi*4 + r;                                          \
                    const int col = sub*16 + lo;                                       \
                    const unsigned byte = (unsigned)(row*128 + (((col>>3) ^ (row&7))*16) + (col&7)*2); \
                    float pv = S1[sub][r] * S2[sub][r];                                \
                    if (DIAG && col > w*16 + row) pv = 0.0f;                           \
                    *(bf16*)((char*)Pl[w] + byte) = (bf16)pv;                          \
                }

        // --- tile b: combine -> P -> PV (V fragments cached in regs) ---
        if (kt == qb) { COMBINE(s1b, s2b, true) } else { COMBINE(s1b, s2b, false) }
        asm volatile("s_waitcnt lgkmcnt(0)" ::: "memory");
        __builtin_amdgcn_sched_barrier(0);

        bf16x8 vfr[2][4];
        __builtin_amdgcn_s_setprio(1);
        #pragma unroll
        for (int ks = 0; ks < 2; ++ks) {
            const unsigned pby = (unsigned)(lo*128 + (((ks*4 + hi) ^ (lo & 7)) * 16));
            bf16x8 pfb = *reinterpret_cast<const bf16x8*>((const char*)Pl[w] + pby);
            #pragma unroll
            for (int n = 0; n < 4; ++n) {
                const unsigned vby = (unsigned)((n*16 + lo)*128 + (((ks*4 + hi) ^ (lo & 7)) * 16));
                vfr[ks][n] = *reinterpret_cast<const bf16x8*>(Vb + vby);
                yaccb[n] = MFMA(pfb, vfr[ks][n], yaccb[n]);
            }
        }
        __builtin_amdgcn_s_setprio(0);

        // --- tile a: combine -> P (reuse buffer) -> PV from cached V regs ---
        if (doA) {
            asm volatile("s_waitcnt lgkmcnt(0)" ::: "memory");
            __builtin_amdgcn_sched_barrier(0);
            if (kt == qa) { COMBINE(s1a, s2a, true) } else { COMBINE(s1a, s2a, false) }
            asm volatile("s_waitcnt lgkmcnt(0)" ::: "memory");
            __builtin_amdgcn_sched_barrier(0);
            __builtin_amdgcn_s_setprio(1);
            #pragma unroll
            for (int ks = 0; ks < 2; ++ks) {
                const unsigned pby = (unsigned)(lo*128 + (((ks*4 + hi) ^ (lo & 7)) * 16));
                bf16x8 pfa = *reinterpret_cast<const bf16x8*>((const char*)Pl[w] + pby);
                #pragma unroll
                for (int n = 0; n < 4; ++n)
                    yacca[n] = MFMA(pfa, vfr[ks][n], yacca[n]);
            }
            __builtin_amdgcn_s_setprio(0);
        }
        #undef COMBINE

        cur += 1; if (cur >= 3) cur -= 3;
    }

    // --- writeout via swizzled per-wave staging, 16B coalesced stores ---
    auto writeOut = [&](int q0, const f32x4* ya) {
        #pragma unroll
        for (int n = 0; n < 4; ++n)
            #pragma unroll
            for (int r = 0; r < 4; ++r) {
                const int row = hi*4 + r;
                const int col = n*16 + lo;
                const unsigned byte = (unsigned)(row*128 + (((col>>3) ^ (row&7))*16) + (col&7)*2);
                *(bf16*)((char*)Pl[w] + byte) = (bf16)ya[n][r];
            }
        asm volatile("s_waitcnt lgkmcnt(0)" ::: "memory");
        __builtin_amdgcn_sched_barrier(0);
        #pragma unroll
        for (int pass = 0; pass < 2; ++pass) {
            const int idx = pass*64 + lane;
            const int row = idx >> 3;
            const int cc  = idx & 7;
            bf16x8 val = *reinterpret_cast<const bf16x8*>(
                (const char*)Pl[w] + row*128 + ((cc ^ (row&7))*16));
            const int t = q0 + w*16 + row;
            const int c = h*ND + cc*8;
            *reinterpret_cast<bf16x8*>(Y + ((size_t)b*NT + t)*NC + c) = val;
        }
    };
    writeOut(qa*64, yacca);
    writeOut(qb*64, yaccb);
}

// ---------------- launch ----------------
extern "C" void kernel_launch(void* const* d_in, const int* in_sizes, int n_in,
                              void* d_out, int out_size, void* d_ws, size_t ws_size,
                              hipStream_t stream)
{
    const float* x = (const float*)d_in[0];

    char* ws = (char*)d_ws;
    bf16*   Xbf   = (bf16*)ws;                                            // 8 MB
    bf16*   Wcat  = (bf16*)(ws + (size_t)NBT*NC*2);                       // 12 MB (6 mats)
    bf16*   QKV   = (bf16*)(ws + (size_t)NBT*NC*2 + (size_t)6*NC*NC*2);   // 40 MB
    bf16*   Ybf   = (bf16*)((char*)QKV + (size_t)5*NBT*NC*2);             // 8 MB
    float2* tbl   = (float2*)((char*)Ybf + (size_t)NBT*NC*2);             // 512 KB
    bf16*   Woutb = Wcat + (size_t)5*NC*NC;

    WPtrs wp;
    wp.p[0] = (const float*)d_in[1]; wp.p[1] = (const float*)d_in[2];
    wp.p[2] = (const float*)d_in[3]; wp.p[3] = (const float*)d_in[4];
    wp.p[4] = (const float*)d_in[5]; wp.p[5] = (const float*)d_in[6];

    // fused prep: X cast + weight casts + rope table
    prep_kernel<<<dim3(10496), 256, 0, stream>>>(x, wp, Xbf, Wcat, tbl);

    // fused 5-projection GEMM (128^2 tile, 3-slot pipeline, 3 blk/CU)
    gemm_proj<<<dim3(1280), 256, 0, stream>>>(Xbf, Wcat, QKV, tbl);
    // fused bilinear attention -> Ybf [b][t][c]  (XCD-local, triple-buffered)
    attn_kernel<<<dim3(512), 256, 0, stream>>>(QKV, Ybf);
    // output projection -> fp32 d_out (128x64 tiles, 4-slot, 3-deep prefetch)
    gemm_out<<<dim3(NC/64, NBT/128), 256, 0, stream>>>(Ybf, Woutb, (float*)d_out);
}